// Round 5
// baseline (125.320 us; speedup 1.0000x reference)
//
#include <hip/hip_runtime.h>

// Depthwise cross-correlation: z (64,256,7,7) over x (64,256,31,31) VALID
// -> out (64,256,25,25), scaled 0.001.
//
// Round 5: rounds 1-4 (all LDS+barrier designs) pinned at 45-51 us,
// latency-bound on the per-block critical path (stage -> barrier -> LDS
// chains -> barrier -> store) at ~2 resident waves/SIMD. This round removes
// LDS and __syncthreads entirely:
//   thread = (slice, out-col ox). Slides down the 31 x rows:
//     - z (49 f32) loaded once into VGPRs (12 dwordx4 + 1)
//     - per x row: 7 floats via two overlapping dwordx4 (dword-aligned ok)
//     - x row r feeds acc[oy] for oy in [r-6, r] cap [0,24] (<=49 FMA/row)
//   L1 absorbs the 7x horizontal re-read (neighbor lanes share lines).
//   Stores: 25 dwords down the column; lanes of a slice-group cover 100 B
//   contiguous per instr.
// Straight-line ~1500-instr stream, no barriers: latency hidden by ILP.
// fp32 end-to-end (absmax back to ~6e-5).

#define KH 7
#define KW 7
#define XH 31
#define XW 31
#define OH 25
#define OW 25
#define NSLICE (64 * 256)
#define THREADS 256

__global__ __launch_bounds__(THREADS)
void xcorr_dw_kernel(const float* __restrict__ z,
                     const float* __restrict__ x,
                     float* __restrict__ out) {
    const int t = blockIdx.x * THREADS + threadIdx.x;  // 0 .. 409599
    const int s  = t / OW;         // slice 0..16383 (exact: 16384*25 threads)
    const int ox = t - s * OW;     // output column 0..24

    // ---- z into registers: 12 overlapping-free dwordx4 + 1 scalar.
    const float* __restrict__ zgp = z + (size_t)s * (KH * KW);
    float zr[KH * KW];
    #pragma unroll
    for (int k = 0; k < 12; ++k) {
        const float4 v = *(const float4*)(zgp + 4 * k);
        zr[4 * k + 0] = v.x; zr[4 * k + 1] = v.y;
        zr[4 * k + 2] = v.z; zr[4 * k + 3] = v.w;
    }
    zr[48] = zgp[48];

    // ---- Slide down x rows; acc[oy] accumulates output column ox.
    const float* __restrict__ xgp = x + (size_t)s * (XH * XW) + ox;
    float acc[OH] = {};
    #pragma unroll
    for (int r = 0; r < XH; ++r) {
        const float* __restrict__ p = xgp + r * XW;
        const float4 a = *(const float4*)(p);        // cols ox .. ox+3
        const float4 b = *(const float4*)(p + 3);    // cols ox+3 .. ox+6
        const float f[KW] = {a.x, a.y, a.z, a.w, b.y, b.z, b.w};
        const int lo = (r - (KH - 1) < 0) ? 0 : r - (KH - 1);
        const int hi = (r < OH - 1) ? r : OH - 1;
        #pragma unroll
        for (int oy = lo; oy <= hi; ++oy) {
            const int i = r - oy;                    // kernel row
            #pragma unroll
            for (int j = 0; j < KW; ++j)
                acc[oy] = fmaf(f[j], zr[i * KW + j], acc[oy]);
        }
    }

    // ---- Store the output column (lanes of a slice-group are contiguous).
    float* __restrict__ og = out + (size_t)s * (OH * OW) + ox;
    #pragma unroll
    for (int oy = 0; oy < OH; ++oy)
        og[oy * OW] = acc[oy] * 0.001f;
}

extern "C" void kernel_launch(void* const* d_in, const int* in_sizes, int n_in,
                              void* d_out, int out_size, void* d_ws, size_t ws_size,
                              hipStream_t stream) {
    const float* z = (const float*)d_in[0];   // (64,256,7,7)
    const float* x = (const float*)d_in[1];   // (64,256,31,31)
    float* out = (float*)d_out;               // (64,256,25,25)
    const int nthreads = NSLICE * OW;                    // 409,600
    const int nblk = nthreads / THREADS;                 // 1600
    xcorr_dw_kernel<<<dim3(nblk), dim3(THREADS), 0, stream>>>(z, x, out);
}

// Round 6
// 116.948 us; speedup vs baseline: 1.0716x; 1.0716x over previous
//
#include <hip/hip_runtime.h>

// Depthwise cross-correlation: z (64,256,7,7) over x (64,256,31,31) VALID
// -> out (64,256,25,25), scaled 0.001. fp32 end-to-end.
//
// Round 6: rounds 1-5 all pinned at 44-51 us, memory-LATENCY-bound (Little's
// law: ~2 MB in flight vs ~5.7 MB needed; R5 occupancy counter showed ~1.3
// runnable waves/SIMD, 74/96 VGPRs pinned by z+acc). Fix: async DMA staging.
//  - global_load_lds dwordx4 (m97 mechanism): no VGPR cost, deep queue.
//    Each 128-thr block stages 5 slices = 10 chunks x 512 dwords async
//    (10 KB in flight/wave); 7 blocks/CU overlap each other's drains.
//  - front-pad trick: block's global base rounded down to 16 B; pre (0..3)
//    dwords of slack at the LDS front. Tail lanes clamp the GLOBAL address
//    (per-lane gather is legal; only the LDS side is lane-contiguous) and
//    land in the LDS pad region.
//  - compute: thread=(slice, out-row); per kernel row read 31 dwords
//    (ds_read2_b32, banks (sl - row + c) mod 32: 961=1, 31=-1 mod 32 ->
//    <=2-3-way, free) feeding 175 independent FMAs. z broadcast from LDS
//    (saves 49 VGPRs -> ~85 total, 4 waves/SIMD >= 3.5-block LDS cap).
//  - stores: per-lane contiguous 100 B (R4 falsified store-scatter cost).

#define KH 7
#define KW 7
#define XH 31
#define XW 31
#define OH 25
#define OW 25
#define NSLICE (64 * 256)
#define SPB 5
#define THREADS 128
#define XS_DW 5120                    // 10 chunks x 512 dwords (pad incl.)
#define ZS_DW 256
#define X_TOTAL_DW (NSLICE * (XH * XW))   // 15,745,024
#define Z_TOTAL_DW (NSLICE * (KH * KW))   // 802,816

__device__ __forceinline__ void gl_lds16(const float* g, float* l) {
    __builtin_amdgcn_global_load_lds(
        (const __attribute__((address_space(1))) void*)g,
        (__attribute__((address_space(3))) void*)l, 16, 0, 0);
}

__global__ __launch_bounds__(THREADS)
void xcorr_dw_kernel(const float* __restrict__ z,
                     const float* __restrict__ x,
                     float* __restrict__ out) {
    __shared__ float xs[XS_DW];       // 20.0 KB
    __shared__ float zs[ZS_DW];       // 1.0 KB
    const int tid = threadIdx.x;
    const int base_slice = blockIdx.x * SPB;
    const int nsl = min(SPB, NSLICE - base_slice);

    // 16-B-aligned global dword bases with front slack pre/prez in [0,3].
    const int g0r  = base_slice * (XH * XW);
    const int pre  = g0r & 3;
    const int g0   = g0r - pre;
    const int zg0r = base_slice * (KH * KW);
    const int prez = zg0r & 3;
    const int zg0  = zg0r - prez;

    // ---- Async stage x: 10 x (2 waves x 64 lanes x 16 B) = 5120 dwords.
    // Needed: pre + nsl*961 <= 4808; excess lanes read a clamped-valid
    // global address and land in the LDS pad.
    #pragma unroll
    for (int k = 0; k < 10; ++k) {
        const int dw  = k * 512 + tid * 4;
        const int gdw = min(g0 + dw, X_TOTAL_DW - 4);
        gl_lds16(x + gdw, xs + dw);
    }
    // ---- Async stage z: one wave covers 256 dwords >= prez + nsl*49.
    if (tid < 64) {
        const int gdw = min(zg0 + tid * 4, Z_TOTAL_DW - 4);
        gl_lds16(z + gdw, zs + tid * 4);
    }
    __syncthreads();   // compiler emits s_waitcnt vmcnt(0) before s_barrier

    // ---- Compute: thread -> (slice, output row). 125 of 128 lanes active.
    const int sl = tid / 25;
    const int oy = tid - sl * 25;
    if (sl < nsl) {
        const float* __restrict__ xrow = xs + pre + sl * (XH * XW);
        const float* __restrict__ zrow = zs + prez + sl * (KH * KW);
        float acc[OW] = {};
        #pragma unroll
        for (int i = 0; i < KH; ++i) {
            const float* __restrict__ p = xrow + (oy + i) * XW;
            float f[XW];
            #pragma unroll
            for (int c = 0; c < XW; ++c) f[c] = p[c];      // ds_read2_b32 x16
            float w[KW];
            #pragma unroll
            for (int j = 0; j < KW; ++j) w[j] = zrow[i * KW + j];  // broadcast
            #pragma unroll
            for (int j = 0; j < KW; ++j) {
                #pragma unroll
                for (int c = 0; c < OW; ++c)
                    acc[c] = fmaf(f[c + j], w[j], acc[c]);
            }
        }
        float* __restrict__ og =
            out + (size_t)(base_slice + sl) * (OH * OW) + oy * OW;
        #pragma unroll
        for (int c = 0; c < OW; ++c) og[c] = acc[c] * 0.001f;
    }
}

extern "C" void kernel_launch(void* const* d_in, const int* in_sizes, int n_in,
                              void* d_out, int out_size, void* d_ws, size_t ws_size,
                              hipStream_t stream) {
    const float* z = (const float*)d_in[0];   // (64,256,7,7)
    const float* x = (const float*)d_in[1];   // (64,256,31,31)
    float* out = (float*)d_out;               // (64,256,25,25)
    const int nblk = (NSLICE + SPB - 1) / SPB;   // 3277
    xcorr_dw_kernel<<<dim3(nblk), dim3(THREADS), 0, stream>>>(z, x, out);
}

// Round 7
// 112.926 us; speedup vs baseline: 1.1097x; 1.0356x over previous
//
#include <hip/hip_runtime.h>

// Depthwise cross-correlation: z (64,256,7,7) over x (64,256,31,31) VALID
// -> out (64,256,25,25), scaled 0.001. fp32 end-to-end.
//
// Round 7 = Round 6 (async global_load_lds staging, which dropped the kernel
// 44 -> ~37 us) + ONE change: coalesced store path.
//   R6 stored 25 dwords/thread at 100-B lane stride: ~60 distinct 64-B
//   granules per store instr -> ~38k store requests/CU at ~1 req/cyc TA
//   ~= 16 us serialized. Now: accs staged into the dead x LDS buffer
//   (3125 dwords <= 5120), then block-flat copy: lane-consecutive dwords,
//   4 granules/instr, ~15x fewer store requests. Cost: ~50 LDS instr/wave
//   + 1 barrier.

#define KH 7
#define KW 7
#define XH 31
#define XW 31
#define OH 25
#define OW 25
#define NSLICE (64 * 256)
#define SPB 5
#define THREADS 128
#define XS_DW 5120                    // 10 chunks x 512 dwords (pad incl.)
#define ZS_DW 256
#define OUT_DW (SPB * OH * OW)        // 3125 <= XS_DW: single-chunk out stage
#define X_TOTAL_DW (NSLICE * (XH * XW))   // 15,745,024
#define Z_TOTAL_DW (NSLICE * (KH * KW))   // 802,816

__device__ __forceinline__ void gl_lds16(const float* g, float* l) {
    __builtin_amdgcn_global_load_lds(
        (const __attribute__((address_space(1))) void*)g,
        (__attribute__((address_space(3))) void*)l, 16, 0, 0);
}

__global__ __launch_bounds__(THREADS)
void xcorr_dw_kernel(const float* __restrict__ z,
                     const float* __restrict__ x,
                     float* __restrict__ out) {
    __shared__ float xs[XS_DW];       // x during compute; out-stage after
    __shared__ float zs[ZS_DW];
    const int tid = threadIdx.x;
    const int base_slice = blockIdx.x * SPB;
    const int nsl = min(SPB, NSLICE - base_slice);

    // 16-B-aligned global dword bases with front slack pre/prez in [0,3].
    const int g0r  = base_slice * (XH * XW);
    const int pre  = g0r & 3;
    const int g0   = g0r - pre;
    const int zg0r = base_slice * (KH * KW);
    const int prez = zg0r & 3;
    const int zg0  = zg0r - prez;

    // ---- Async stage x: 10 x (2 waves x 64 lanes x 16 B) = 5120 dwords.
    #pragma unroll
    for (int k = 0; k < 10; ++k) {
        const int dw  = k * 512 + tid * 4;
        const int gdw = min(g0 + dw, X_TOTAL_DW - 4);
        gl_lds16(x + gdw, xs + dw);
    }
    // ---- Async stage z: one wave covers 256 dwords >= prez + nsl*49.
    if (tid < 64) {
        const int gdw = min(zg0 + tid * 4, Z_TOTAL_DW - 4);
        gl_lds16(z + gdw, zs + tid * 4);
    }
    __syncthreads();   // waitcnt vmcnt(0) + barrier

    // ---- Compute: thread -> (slice, output row). 125 of 128 lanes active.
    const int sl = tid / 25;
    const int oy = tid - sl * 25;
    const bool active = (sl < nsl);
    float acc[OW] = {};
    if (active) {
        const float* __restrict__ xrow = xs + pre + sl * (XH * XW);
        const float* __restrict__ zrow = zs + prez + sl * (KH * KW);
        #pragma unroll
        for (int i = 0; i < KH; ++i) {
            const float* __restrict__ p = xrow + (oy + i) * XW;
            float f[XW];
            #pragma unroll
            for (int c = 0; c < XW; ++c) f[c] = p[c];      // ds_read2_b32 x16
            float w[KW];
            #pragma unroll
            for (int j = 0; j < KW; ++j) w[j] = zrow[i * KW + j];  // broadcast
            #pragma unroll
            for (int j = 0; j < KW; ++j) {
                #pragma unroll
                for (int c = 0; c < OW; ++c)
                    acc[c] = fmaf(f[c + j], w[j], acc[c]);
            }
        }
    }
    __syncthreads();   // all xs reads done; xs becomes the out-stage buffer

    // ---- Stage accs in LDS: addr = 625*sl + 25*oy + c -> banks
    // (17*sl + 25*oy + c) mod 32, near-uniform (<=2-3 way).
    if (active) {
        const int fbase = sl * (OH * OW) + oy * OW;
        #pragma unroll
        for (int c = 0; c < OW; ++c) xs[fbase + c] = acc[c] * 0.001f;
    }
    __syncthreads();

    // ---- Block-flat coalesced copy: 64 consecutive dwords per wave-instr
    // = 4 granules (vs ~60 for the scattered per-lane-row stores).
    const int n_out = nsl * (OH * OW);
    float* __restrict__ og = out + (size_t)base_slice * (OH * OW);
    for (int d = tid; d < n_out; d += THREADS) og[d] = xs[d];
}

extern "C" void kernel_launch(void* const* d_in, const int* in_sizes, int n_in,
                              void* d_out, int out_size, void* d_ws, size_t ws_size,
                              hipStream_t stream) {
    const float* z = (const float*)d_in[0];   // (64,256,7,7)
    const float* x = (const float*)d_in[1];   // (64,256,31,31)
    float* out = (float*)d_out;               // (64,256,25,25)
    const int nblk = (NSLICE + SPB - 1) / SPB;   // 3277
    xcorr_dw_kernel<<<dim3(nblk), dim3(THREADS), 0, stream>>>(z, x, out);
}